// Round 1
// baseline (1199.830 us; speedup 1.0000x reference)
//
#include <hip/hip_runtime.h>

typedef _Float16 hx8 __attribute__((ext_vector_type(8)));
typedef float    fx4 __attribute__((ext_vector_type(4)));

constexpr int T_ = 4608;   // tokens = 8*576
constexpr int D_ = 1024;
constexpr int H_ = 4096;
constexpr int C_ = 4096;
constexpr int E_ = 8;
constexpr int BM = 128;                 // row-tile (tokens) for both GEMMs
constexpr int PADROWS = T_ * 2 + E_ * BM;  // 10240 padded bucket rows

// ---------------- routing: logits, top-2, softmax, x -> fp16 ----------------
__global__ __launch_bounds__(256) void k_route(
    const float* __restrict__ x, const float* __restrict__ sw,
    const float* __restrict__ sb, _Float16* __restrict__ xh,
    int* __restrict__ meta, int* __restrict__ e0a, int* __restrict__ e1a,
    float* __restrict__ w0a, float* __restrict__ w1a)
{
    __shared__ float ssw[E_ * D_];           // 32 KiB
    const int tid = threadIdx.x;
    for (int i = tid; i < E_ * D_ / 4; i += 256)
        reinterpret_cast<fx4*>(ssw)[i] = reinterpret_cast<const fx4*>(sw)[i];
    __syncthreads();

    const int wid = tid >> 6, lane = tid & 63;
    const int t = blockIdx.x * 4 + wid;      // grid = T/4, always in range
    const float* xr = x + (size_t)t * D_;
    _Float16* xhr = xh + (size_t)t * D_;

    float acc[E_] = {};
    for (int i = lane; i < D_; i += 64) {
        float xv = xr[i];
        xhr[i] = (_Float16)xv;
        #pragma unroll
        for (int e = 0; e < E_; e++) acc[e] += xv * ssw[e * D_ + i];
    }
    #pragma unroll
    for (int e = 0; e < E_; e++) {
        float v = acc[e];
        #pragma unroll
        for (int o = 32; o > 0; o >>= 1) v += __shfl_xor(v, o, 64);
        acc[e] = v;
    }
    if (lane == 0) {
        float l[E_];
        #pragma unroll
        for (int e = 0; e < E_; e++) l[e] = acc[e] + sb[e];
        int b0 = 0; float v0 = l[0];
        #pragma unroll
        for (int e = 1; e < E_; e++) if (l[e] > v0) { v0 = l[e]; b0 = e; }
        int b1 = -1; float v1 = -3.4e38f;
        #pragma unroll
        for (int e = 0; e < E_; e++) if (e != b0 && l[e] > v1) { v1 = l[e]; b1 = e; }
        float r = __expf(v1 - v0);           // <= 1
        float inv = 1.f / (1.f + r);
        e0a[t] = b0; e1a[t] = b1; w0a[t] = inv; w1a[t] = r * inv;
        atomicAdd(&meta[b0], 1);
        atomicAdd(&meta[b1], 1);
    }
}

// ---------------- scan: padded offsets ----------------
__global__ void k_scan(int* meta)
{
    if (threadIdx.x == 0) {
        int off = 0;
        for (int e = 0; e < E_; e++) {
            meta[16 + e] = off;
            off += ((meta[e] + BM - 1) / BM) * BM;
        }
        meta[24] = off;
    }
}

// ---------------- scatter tokens into expert buckets ----------------
__global__ void k_scatter(int* __restrict__ meta,
                          const int* __restrict__ e0a, const int* __restrict__ e1a,
                          const float* __restrict__ w0a, const float* __restrict__ w1a,
                          int* __restrict__ tok, float* __restrict__ gate)
{
    int t = blockIdx.x * 256 + threadIdx.x;
    if (t >= T_) return;
    int* cursors = meta + 8;
    const int* padoff = meta + 16;
    int e0 = e0a[t];
    int s0 = atomicAdd(&cursors[e0], 1);
    tok[padoff[e0] + s0] = t; gate[padoff[e0] + s0] = w0a[t];
    int e1 = e1a[t];
    int s1 = atomicAdd(&cursors[e1], 1);
    tok[padoff[e1] + s1] = t; gate[padoff[e1] + s1] = w1a[t];
}

// ---------------- GEMM1: h = silu(x W1^T + b1) * (x W3^T + b3) ----------------
// tile: BM=128 rows x 64 hcols, BK=32, 256 threads (4 waves of 64x32)
__global__ __launch_bounds__(256) void k_gemm1(
    const _Float16* __restrict__ xh,
    const float* __restrict__ w1, const float* __restrict__ b1,
    const float* __restrict__ w3, const float* __restrict__ b3,
    const int* __restrict__ meta, const int* __restrict__ tok,
    _Float16* __restrict__ hbuf)
{
    const int e = blockIdx.z;
    const int n_e = meta[e];
    const int row0 = blockIdx.y * BM;
    if (row0 >= n_e) return;
    const int col0 = blockIdx.x * 64;
    const int prow0 = meta[16 + e] + row0;

    __shared__ _Float16 sA[128][40];
    __shared__ _Float16 sB1[64][40];
    __shared__ _Float16 sB3[64][40];

    const int tid = threadIdx.x;
    // A staging: 4 thr/row, 8 halves each; rows ar and ar+64 (gathered tokens)
    const int ar = tid >> 2, ac = (tid & 3) * 8;
    const int i0 = (row0 + ar      < n_e) ? ar      : 0;
    const int i1 = (row0 + ar + 64 < n_e) ? ar + 64 : 0;
    const int t0 = tok[prow0 + i0];
    const int t1 = tok[prow0 + i1];
    const _Float16* a0p = xh + (size_t)t0 * D_ + ac;
    const _Float16* a1p = xh + (size_t)t1 * D_ + ac;
    // B staging: 4 thr/row over 64 rows, 8 floats each
    const int br = tid >> 2, bc = (tid & 3) * 8;
    const float* w1p = w1 + ((size_t)e * H_ + col0 + br) * D_ + bc;
    const float* w3p = w3 + ((size_t)e * H_ + col0 + br) * D_ + bc;

    const int lane = tid & 63, wid = tid >> 6;
    const int wr = (wid >> 1) * 64, wc = (wid & 1) * 32;
    const int fr = lane & 15, kg = (lane >> 4) * 8;

    fx4 acc1[4][2] = {};
    fx4 acc3[4][2] = {};

    for (int kk = 0; kk < D_; kk += 32) {
        __syncthreads();
        *(hx8*)&sA[ar][ac]      = *(const hx8*)(a0p + kk);
        *(hx8*)&sA[ar + 64][ac] = *(const hx8*)(a1p + kk);
        {
            fx4 f0 = *(const fx4*)(w1p + kk);
            fx4 f1 = *(const fx4*)(w1p + kk + 4);
            hx8 hv;
            hv[0]=(_Float16)f0[0]; hv[1]=(_Float16)f0[1]; hv[2]=(_Float16)f0[2]; hv[3]=(_Float16)f0[3];
            hv[4]=(_Float16)f1[0]; hv[5]=(_Float16)f1[1]; hv[6]=(_Float16)f1[2]; hv[7]=(_Float16)f1[3];
            *(hx8*)&sB1[br][bc] = hv;
            fx4 g0 = *(const fx4*)(w3p + kk);
            fx4 g1 = *(const fx4*)(w3p + kk + 4);
            hx8 gv;
            gv[0]=(_Float16)g0[0]; gv[1]=(_Float16)g0[1]; gv[2]=(_Float16)g0[2]; gv[3]=(_Float16)g0[3];
            gv[4]=(_Float16)g1[0]; gv[5]=(_Float16)g1[1]; gv[6]=(_Float16)g1[2]; gv[7]=(_Float16)g1[3];
            *(hx8*)&sB3[br][bc] = gv;
        }
        __syncthreads();
        hx8 af[4];
        #pragma unroll
        for (int mi = 0; mi < 4; mi++)
            af[mi] = *(const hx8*)&sA[wr + mi * 16 + fr][kg];
        #pragma unroll
        for (int ni = 0; ni < 2; ni++) {
            hx8 bf1 = *(const hx8*)&sB1[wc + ni * 16 + fr][kg];
            hx8 bf3 = *(const hx8*)&sB3[wc + ni * 16 + fr][kg];
            #pragma unroll
            for (int mi = 0; mi < 4; mi++) {
                acc1[mi][ni] = __builtin_amdgcn_mfma_f32_16x16x32_f16(af[mi], bf1, acc1[mi][ni], 0, 0, 0);
                acc3[mi][ni] = __builtin_amdgcn_mfma_f32_16x16x32_f16(af[mi], bf3, acc3[mi][ni], 0, 0, 0);
            }
        }
    }

    #pragma unroll
    for (int ni = 0; ni < 2; ni++) {
        const int col = col0 + wc + ni * 16 + fr;
        const float bb1 = b1[(size_t)e * H_ + col];
        const float bb3 = b3[(size_t)e * H_ + col];
        #pragma unroll
        for (int mi = 0; mi < 4; mi++) {
            const int rbase = wr + mi * 16 + (lane >> 4) * 4;
            #pragma unroll
            for (int j = 0; j < 4; j++) {
                const int r = rbase + j;
                if (row0 + r < n_e) {
                    float v1 = acc1[mi][ni][j] + bb1;
                    float v3 = acc3[mi][ni][j] + bb3;
                    float hv = v1 * v3 / (1.f + __expf(-v1));   // silu(v1)*v3
                    hbuf[(size_t)(prow0 + r) * H_ + col] = (_Float16)hv;
                }
            }
        }
    }
}

// ---------------- GEMM2: out += gate * (h W2^T + b2) ----------------
// tile: BM=128 rows x 128 cols, BK=32, 256 threads (4 waves of 64x64)
__global__ __launch_bounds__(256) void k_gemm2(
    const _Float16* __restrict__ hbuf,
    const float* __restrict__ w2, const float* __restrict__ b2,
    const int* __restrict__ meta, const int* __restrict__ tok,
    const float* __restrict__ gate, float* __restrict__ out)
{
    const int e = blockIdx.z;
    const int n_e = meta[e];
    const int row0 = blockIdx.y * BM;
    if (row0 >= n_e) return;
    const int col0 = blockIdx.x * 128;
    const int prow0 = meta[16 + e] + row0;

    __shared__ _Float16 sA[128][40];
    __shared__ _Float16 sB[128][40];

    const int tid = threadIdx.x;
    const int ar = tid >> 2, ac = (tid & 3) * 8;
    const _Float16* a0p = hbuf + (size_t)(prow0 + ar) * H_ + ac;
    const _Float16* a1p = hbuf + (size_t)(prow0 + ar + 64) * H_ + ac;
    const int br = tid >> 2, bc = (tid & 3) * 8;
    const float* p0 = w2 + ((size_t)e * C_ + col0 + br) * H_ + bc;
    const float* p1 = w2 + ((size_t)e * C_ + col0 + br + 64) * H_ + bc;

    const int lane = tid & 63, wid = tid >> 6;
    const int wr = (wid >> 1) * 64, wc = (wid & 1) * 64;
    const int fr = lane & 15, kg = (lane >> 4) * 8;

    fx4 acc[4][4] = {};

    for (int kk = 0; kk < H_; kk += 32) {
        __syncthreads();
        *(hx8*)&sA[ar][ac]      = *(const hx8*)(a0p + kk);
        *(hx8*)&sA[ar + 64][ac] = *(const hx8*)(a1p + kk);
        {
            fx4 f0 = *(const fx4*)(p0 + kk);
            fx4 f1 = *(const fx4*)(p0 + kk + 4);
            hx8 hv;
            hv[0]=(_Float16)f0[0]; hv[1]=(_Float16)f0[1]; hv[2]=(_Float16)f0[2]; hv[3]=(_Float16)f0[3];
            hv[4]=(_Float16)f1[0]; hv[5]=(_Float16)f1[1]; hv[6]=(_Float16)f1[2]; hv[7]=(_Float16)f1[3];
            *(hx8*)&sB[br][bc] = hv;
            fx4 g0 = *(const fx4*)(p1 + kk);
            fx4 g1 = *(const fx4*)(p1 + kk + 4);
            hx8 gv;
            gv[0]=(_Float16)g0[0]; gv[1]=(_Float16)g0[1]; gv[2]=(_Float16)g0[2]; gv[3]=(_Float16)g0[3];
            gv[4]=(_Float16)g1[0]; gv[5]=(_Float16)g1[1]; gv[6]=(_Float16)g1[2]; gv[7]=(_Float16)g1[3];
            *(hx8*)&sB[br + 64][bc] = gv;
        }
        __syncthreads();
        hx8 af[4], bf[4];
        #pragma unroll
        for (int mi = 0; mi < 4; mi++)
            af[mi] = *(const hx8*)&sA[wr + mi * 16 + fr][kg];
        #pragma unroll
        for (int ni = 0; ni < 4; ni++)
            bf[ni] = *(const hx8*)&sB[wc + ni * 16 + fr][kg];
        #pragma unroll
        for (int ni = 0; ni < 4; ni++)
            #pragma unroll
            for (int mi = 0; mi < 4; mi++)
                acc[mi][ni] = __builtin_amdgcn_mfma_f32_16x16x32_f16(af[mi], bf[ni], acc[mi][ni], 0, 0, 0);
    }

    #pragma unroll
    for (int ni = 0; ni < 4; ni++) {
        const int col = col0 + wc + ni * 16 + fr;
        const float bb = b2[(size_t)e * C_ + col];
        #pragma unroll
        for (int mi = 0; mi < 4; mi++) {
            const int rbase = wr + mi * 16 + (lane >> 4) * 4;
            #pragma unroll
            for (int j = 0; j < 4; j++) {
                const int r = rbase + j;
                if (row0 + r < n_e) {
                    const int prow = prow0 + r;
                    const int tkn = tok[prow];
                    const float g = gate[prow];
                    atomicAdd(&out[(size_t)tkn * C_ + col], g * (acc[mi][ni][j] + bb));
                }
            }
        }
    }
}

// ---------------- launch ----------------
extern "C" void kernel_launch(void* const* d_in, const int* in_sizes, int n_in,
                              void* d_out, int out_size, void* d_ws, size_t ws_size,
                              hipStream_t stream)
{
    const float* x  = (const float*)d_in[0];
    const float* sw = (const float*)d_in[1];
    const float* sb = (const float*)d_in[2];
    const float* w1 = (const float*)d_in[3];
    const float* b1 = (const float*)d_in[4];
    const float* w2 = (const float*)d_in[5];
    const float* b2 = (const float*)d_in[6];
    const float* w3 = (const float*)d_in[7];
    const float* b3 = (const float*)d_in[8];
    float* out = (float*)d_out;

    char* ws = (char*)d_ws;
    int*      meta  = (int*)ws;                                   // [0..7] cnt, [8..15] cur, [16..24] padoff
    int*      e0a   = (int*)  (ws + 256);
    int*      e1a   = (int*)  (ws + 256 + 4 * (size_t)T_);
    float*    w0a   = (float*)(ws + 256 + 8 * (size_t)T_);
    float*    w1a   = (float*)(ws + 256 + 12 * (size_t)T_);
    int*      tokb  = (int*)  (ws + 256 + 16 * (size_t)T_);
    float*    gateb = (float*)(ws + 256 + 16 * (size_t)T_ + 4 * (size_t)PADROWS);
    _Float16* xh    = (_Float16*)(ws + 256 + 16 * (size_t)T_ + 8 * (size_t)PADROWS);
    _Float16* hbuf  = (_Float16*)(ws + 256 + 16 * (size_t)T_ + 8 * (size_t)PADROWS
                                  + 2 * (size_t)T_ * D_);

    hipMemsetAsync(d_out, 0, sizeof(float) * (size_t)T_ * C_, stream);
    hipMemsetAsync(meta, 0, 256, stream);

    k_route<<<T_ / 4, 256, 0, stream>>>(x, sw, sb, xh, meta, e0a, e1a, w0a, w1a);
    k_scan<<<1, 1, 0, stream>>>(meta);
    k_scatter<<<(T_ + 255) / 256, 256, 0, stream>>>(meta, e0a, e1a, w0a, w1a, tokb, gateb);
    k_gemm1<<<dim3(H_ / 64, T_ / BM, E_), 256, 0, stream>>>(xh, w1, b1, w3, b3, meta, tokb, hbuf);
    k_gemm2<<<dim3(C_ / 128, T_ / BM, E_), 256, 0, stream>>>(hbuf, w2, b2, meta, tokb, gateb, out);
}